// Round 8
// baseline (5119.967 us; speedup 1.0000x reference)
//
#include <hip/hip_runtime.h>
#include <math.h>

// Problem: MPMatcher  S=6, B=16, L=8, M=256, K=128
// Phase 1 (PASSING, DO NOT TOUCH): cost f32, ocml logf, *(1/6) reciprocal mean.
// Phase 2: reference's buggy greedy walk. R19 = R18 + correct 2-pass fixup.
// R18's bug: deltas can be NEGATIVE in this buggy walk (no minv memory), so a
// used col's v can INCREASE at commit (amt<0) -> its value C-v DECREASES ->
// any row's cached argmin can move to it. R18 only recomputed rows whose
// cached argmin was a used col (valid only for amt>=0). R19 commit fixup:
//   Pass A: rows whose cached argmin IS a used col -> full re-min (new v).
//   Pass B: merge every used col's new value fl(C[r][a]-v_a) into ALL rows'
//           (cmin,cjmin) with lowest-j ties. No-op for value-increased cols
//           (proven), repairs value-decreased cols, idempotent on A-rows.
// Rest identical to R18:
//   - row-min cache (cmin/cjmin over real cols), O(1) fast-path iterations
//   - SELBEST dummy queue depth 2 (R13/R14-proven), refilled on march
//   - deferred duals (R15-proven reals via Ua; R14-proven dummies via Dcons)
//   - accepted 1-ulp regroup class: fl(fl(C-v)-u) vs ref fl(fl(C-u)-v)

#define S_ 6
#define B_ 16
#define L_ 8
#define M_ 256
#define K_ 128

// ---------------------------------------------------------------- cost kernel
__global__ void cost_kernel(const float* __restrict__ mp,   // (6,16,8,256,2)
                            const float* __restrict__ mv,   // (6,16,256,1)
                            const float* __restrict__ gt,   // (6,16,128,2)
                            const float* __restrict__ gv,   // (6,16,128,1)
                            float* __restrict__ cost)       // (16,256,128)
{
#pragma clang fp contract(off)
    const int b = blockIdx.x;
    const int m = blockIdx.y;
    const int k = threadIdx.x;

    float accS = 0.0f;
    for (int s = 0; s < S_; ++s) {
        const int sb = s * B_ + b;
        const float gx = gt[(sb * K_ + k) * 2 + 0];
        const float gy = gt[(sb * K_ + k) * 2 + 1];
        float accL = 0.0f;
#pragma unroll
        for (int l = 0; l < L_; ++l) {
            const int base = ((sb * L_ + l) * M_ + m) * 2;
            const float dx = fabsf(mp[base + 0] - gx);
            const float dy = fabsf(mp[base + 1] - gy);
            const float diff = dx + dy;
            const float dl = (float)(L_ - (l + 1)) * 0.05f;
            const float t = diff - dl;
            accL += fmaxf(t, 0.0f);
        }
        const float meanL = accL * 0.125f;
        const float mvv = mv[sb * M_ + m];
        const float gtv = gv[sb * K_ + k];
        const float lp = -logf(mvv);
        const float ln = -logf(1.0f - mvv);
        const float val = (gtv != 0.0f) ? (5.0f * meanL + lp) : ln;
        accS += val;
    }
    cost[(b * M_ + m) * K_ + k] = accS * (1.0f / 6.0f);
}

// --------------------------------------------------------------- bit helpers
__device__ __forceinline__ double bits2d(int lo, int hi) {
    const unsigned long long u =
        ((unsigned long long)(unsigned)hi << 32) | (unsigned)lo;
    return __longlong_as_double((long long)u);
}
__device__ __forceinline__ void d2bits(double d, int& lo, int& hi) {
    const unsigned long long u = (unsigned long long)__double_as_longlong(d);
    lo = (int)(u & 0xffffffffull);
    hi = (int)(u >> 32);
}
__device__ __forceinline__ double readlane_d(double d, int l) {
    int lo, hi; d2bits(d, lo, hi);
    return bits2d(__builtin_amdgcn_readlane(lo, l),
                  __builtin_amdgcn_readlane(hi, l));
}

// one DPP reduction stage on a (lo,hi) f64 register pair with combiner FOP
#define RSTG(LOV, HIV, FOP, CTRL, RM)                                            \
    {                                                                            \
        const int nlo_ = __builtin_amdgcn_update_dpp(LOV, LOV, CTRL, RM, 0xf, false); \
        const int nhi_ = __builtin_amdgcn_update_dpp(HIV, HIV, CTRL, RM, 0xf, false); \
        const double r_ = FOP(bits2d(LOV, HIV), bits2d(nlo_, nhi_));             \
        d2bits(r_, LOV, HIV);                                                    \
    }
#define RLADDER(LOV, HIV, FOP)                                                   \
    RSTG(LOV, HIV, FOP, 0x111, 0xf)  /* row_shr:1  */                            \
    RSTG(LOV, HIV, FOP, 0x112, 0xf)  /* row_shr:2  */                            \
    RSTG(LOV, HIV, FOP, 0x114, 0xf)  /* row_shr:4  */                            \
    RSTG(LOV, HIV, FOP, 0x118, 0xf)  /* row_shr:8  */                            \
    RSTG(LOV, HIV, FOP, 0x142, 0xa)  /* row_bcast:15 -> rows 1,3 */              \
    RSTG(LOV, HIV, FOP, 0x143, 0xc)  /* row_bcast:31 -> rows 2,3 */

// f32 single-word DPP min stage (for cache init)
#define FSTG(W, CTRL, RM)                                                        \
    {                                                                            \
        const int nw_ = __builtin_amdgcn_update_dpp(W, W, CTRL, RM, 0xf, false); \
        const float f_ = fminf(__int_as_float(W), __int_as_float(nw_));          \
        W = __float_as_int(f_);                                                  \
    }

// best free dummy by (v desc, j asc), excluding used dummy bits and col EXJ1.
// Exhausted -> VOUT = -INF (dval = +INF, never marched). R13/R14-proven.
#define SELBEST(EXJ1, JOUT, VOUT, UOUT)                                          \
    {                                                                            \
        const double vm2_ = ((used & 4) || (jd2 == (EXJ1))) ? NINF : v2;         \
        const double vm3_ = ((used & 8) || (jd3 == (EXJ1))) ? NINF : v3;         \
        const double bx_ = fmax(vm2_, vm3_);                                     \
        int xlo_, xhi_; d2bits(bx_, xlo_, xhi_);                                 \
        RLADDER(xlo_, xhi_, fmax)                                                \
        VOUT = bits2d(__builtin_amdgcn_readlane(xlo_, 63),                       \
                      __builtin_amdgcn_readlane(xhi_, 63));                      \
        int jc_ = BIG;                                                           \
        if (vm3_ == VOUT) jc_ = jd3;                                             \
        if (vm2_ == VOUT) jc_ = jd2;   /* lower j wins within lane */            \
        const unsigned long long bd_ = __ballot(jc_ != BIG);                     \
        JOUT = __builtin_amdgcn_readlane(jc_, (int)__builtin_ctzll(bd_));        \
        const int ol_ = ((JOUT) - 129) >> 1, sl_ = ((JOUT) - 129) & 1;           \
        UOUT = readlane_d(sl_ ? up3 : up2, ol_);                                 \
    }

// ------------------------------------------------------------- matcher kernel
// One wave per batch. Lane owns real cols j=2*lane+1, 2*lane+2 (slots 0,1)
// and dummy cols j=2*lane+129, 2*lane+130 (slots 2,3).
__global__ __launch_bounds__(64, 1) void match_kernel(const float* __restrict__ cost,
                                                      int* __restrict__ out)
{
#pragma clang fp contract(off)
    const int b = blockIdx.x;
    const int lane = threadIdx.x;   // 0..63
    const float* C = cost + (size_t)b * M_ * K_;
    const double INF = __builtin_inf();
    const double NINF = -__builtin_inf();
    const int BIG = 0x7fffffff;

    __shared__ float  C_lds[M_ * K_];   // 128 KB cost slab
    __shared__ double u_lds[257];       // u[0..256], 1-based rows
    __shared__ int    p_lds[257];       // p[j]; 0 = free
    __shared__ double vd_lds[128];      // v of dummy cols 129..256
    __shared__ double cmin_lds[256];    // per-row min of fl(C[r][j] - v_j)
    __shared__ int    cjmin_lds[256];   // its lowest-j argmin (1-based col)
    __shared__ double Dcons[128];       // usum at consumption of log slot t
    __shared__ int    clog[128];        // consumption log: dummy col j

    for (int t = lane; t < (M_ * K_) / 4; t += 64)
        ((float4*)C_lds)[t] = ((const float4*)C)[t];
    for (int t = lane; t < 257; t += 64) {
        u_lds[t] = 0.0;
        p_lds[t] = (t >= 129) ? (t - 128) : 0;
    }
    for (int t = lane; t < 128; t += 64) vd_lds[t] = 0.0;
    __syncthreads();

    // ---- cache init (v = 0): cmin[r] = min_j C[r][j] exactly (f64 promote of
    // f32 min is the f64 min; C - 0.0 is exact), cjmin = lowest-j argmin.
    for (int r = 0; r < 256; ++r) {
        const float a  = C_lds[r * K_ + lane];
        const float c2 = C_lds[r * K_ + 64 + lane];
        int w = __float_as_int(fminf(a, c2));
        FSTG(w, 0x111, 0xf) FSTG(w, 0x112, 0xf) FSTG(w, 0x114, 0xf)
        FSTG(w, 0x118, 0xf) FSTG(w, 0x142, 0xa) FSTG(w, 0x143, 0xc)
        const float mval = __int_as_float(__builtin_amdgcn_readlane(w, 63));
        const unsigned long long ba = __ballot(a == mval);
        const unsigned long long bb = __ballot(c2 == mval);
        const int col = ba ? (int)__builtin_ctzll(ba)
                           : 64 + (int)__builtin_ctzll(bb);   // 0-based
        if (lane == 0) { cmin_lds[r] = (double)mval; cjmin_lds[r] = col + 1; }
    }
    __syncthreads();

    double v0 = 0.0, v1 = 0.0;        // real column potentials (persist)
    const int jd2 = 2 * lane + 129;
    const int jd3 = 2 * lane + 130;

    for (int i = 129; i <= 256; ++i) {
        // ---- walk prologue: snapshots (proven valid R11/R14/R15)
        const int pj0 = p_lds[2 * lane + 1];
        const int pj1 = p_lds[2 * lane + 2];
        const double up0 = u_lds[pj0], up1 = u_lds[pj1];
        const double up2 = u_lds[2 * lane + 1];   // u of dummy jd2's row
        const double up3 = u_lds[2 * lane + 2];   // u of dummy jd3's row
        const double v2 = vd_lds[2 * lane];
        const double v3 = vd_lds[2 * lane + 1];

        double u_i0 = 0.0;
        int used = 0;            // bits 1,2 = real slots; 4,8 = dummy consumed
        double usum = 0.0;
        double Ua0 = 0.0, Ua1 = 0.0;
        int j1 = 0;
        int ptr = 0;
        int jU0 = 0, jU1 = 0, jU2 = 0, jU3 = 0, nU = 0;  // used-real col list

        // candidate queue (depth 2) + cache entries of their target rows
        int jdH, jdQ; double vdH, vdQ, udH, udQ;
        SELBEST(-1, jdH, vdH, udH)
        SELBEST(jdH, jdQ, vdQ, udQ)
        double cmH = cmin_lds[jdH - 129]; int cjH = cjmin_lds[jdH - 129];
        double cmQ = cmin_lds[jdQ - 129]; int cjQ = cjmin_lds[jdQ - 129];

        int r0 = i - 1;                        // current row, 0-based
        double cmC = cmin_lds[r0]; int cjC = cjmin_lds[r0];

        for (;;) {
            const double dval = (0.0 - u_i0) - vdH;   // exact ref order
            double rmin; int rj = 0;
            const bool cached_ok = (nU < 5) && (cjC != jU0) && (cjC != jU1)
                                            && (cjC != jU2) && (cjC != jU3);
            if (cached_ok) {
                // cached argmin free -> it IS the lowest-j free argmin; value
                // regroup fl(fl(C-v)-u) vs ref fl(fl(C-u)-v): accepted 1-ulp
                rmin = cmC - u_i0;
                rj = cjC;
            } else {
                // fallback: exact R15 ladder over free reals
                double cd0 = ((double)C_lds[r0 * K_ + 2 * lane] - u_i0) - v0;
                double cd1 = ((double)C_lds[r0 * K_ + 2 * lane + 1] - u_i0) - v1;
                if (used & 1) cd0 = INF;
                if (used & 2) cd1 = INF;
                double bv = fmin(cd0, cd1);
                int lo, hi; d2bits(bv, lo, hi);
                RLADDER(lo, hi, fmin)
                rmin = bits2d(__builtin_amdgcn_readlane(lo, 63),
                              __builtin_amdgcn_readlane(hi, 63));
                int jr = BIG;
                if (cd1 == rmin) jr = 2 * lane + 2;
                if (cd0 == rmin) jr = 2 * lane + 1;
                const unsigned long long br = __ballot(jr != BIG);
                if (br) rj = __builtin_amdgcn_readlane(jr, (int)__builtin_ctzll(br));
            }

            if (rmin <= dval) {
                // ---- real column wins (ref: real j < dummy j at ties)
                const double delta = rmin;
                usum += delta;
                j1 = rj;
                const int ol = (j1 - 1) >> 1, sl = (j1 - 1) & 1;
                const int i0n = __builtin_amdgcn_readlane(sl ? pj1 : pj0, ol);
                if (i0n == 0) break;    // free real column -> augment
                const double u_n = readlane_d(sl ? up1 : up0, ol);
                if (lane == ol) {
                    used |= (1 << sl);
                    if (sl == 0) Ua0 = usum; else Ua1 = usum;
                }
                if (nU == 0) jU0 = j1; else if (nU == 1) jU1 = j1;
                else if (nU == 2) jU2 = j1; else if (nU == 3) jU3 = j1;
                ++nU;                   // nU >= 5 forces slow path (correct)
                u_i0 = u_n;
                r0 = i0n - 1;
                cmC = cmin_lds[r0]; cjC = cjmin_lds[r0];
            } else {
                // ---- march through head dummy: all operands pre-staged
                const double delta = dval;
                usum += delta;
                if (lane == 0) { clog[ptr] = jdH; Dcons[ptr] = usum; }
                const int olc = (jdH - 129) >> 1, slc = (jdH - 129) & 1;
                if (lane == olc) used |= (4 << slc);
                ++ptr;
                u_i0 = udH;
                r0 = jdH - 129;
                cmC = cmH; cjC = cjH;
                jdH = jdQ; vdH = vdQ; udH = udQ; cmH = cmQ; cjH = cjQ;
                int jdN; double vdN, udN;
                SELBEST(jdH, jdN, vdN, udN)       // refill, consumed >=2 later
                jdQ = jdN; vdQ = vdN; udQ = udN;
                cmQ = cmin_lds[jdQ - 129]; cjQ = cjmin_lds[jdQ - 129];
            }
        }

        // ---- commit: deferred duals (R15/R14 proven formulas)
        __syncthreads();
        if (used & 1) { const double a = usum - Ua0; u_lds[pj0] = up0 + a; v0 -= a; }
        if (used & 2) { const double a = usum - Ua1; u_lds[pj1] = up1 + a; v1 -= a; }
        if (lane < ptr) {
            const int j = clog[lane];
            const double amt = usum - Dcons[lane];
            u_lds[j - 128] += amt;
            vd_lds[j - 129] -= amt;
        }
        if (lane + 64 < ptr) {
            const int j = clog[lane + 64];
            const double amt = usum - Dcons[lane + 64];
            u_lds[j - 128] += amt;
            vd_lds[j - 129] -= amt;
        }
        if (lane == 0) { p_lds[j1] = i; u_lds[i] = usum; }
        __syncthreads();

        // ---- Pass A: rows whose cached argmin is a this-walk-used real col
        // (their cached VALUE is invalid; full re-min with committed v)
        if (nU > 0) {
            int cjs[4], ubs[4];
#pragma unroll
            for (int g = 0; g < 4; ++g) cjs[g] = cjmin_lds[lane + 64 * g];
#pragma unroll
            for (int g = 0; g < 4; ++g) {
                const int ow = (cjs[g] - 1) >> 1;
                ubs[g] = __builtin_amdgcn_ds_bpermute(ow << 2, used);
            }
#pragma unroll
            for (int g = 0; g < 4; ++g) {
                const int sb = (cjs[g] - 1) & 1;
                const bool flag = ((ubs[g] >> sb) & 1) != 0;
                unsigned long long fb = __ballot(flag);
                while (fb) {
                    const int ln = (int)__builtin_ctzll(fb);
                    fb &= fb - 1;
                    const int rr = ln + 64 * g;
                    const double c0 = (double)C_lds[rr * K_ + 2 * lane] - v0;
                    const double c1 = (double)C_lds[rr * K_ + 2 * lane + 1] - v1;
                    double bv2 = fmin(c0, c1);
                    int lo, hi; d2bits(bv2, lo, hi);
                    RLADDER(lo, hi, fmin)
                    const double m = bits2d(__builtin_amdgcn_readlane(lo, 63),
                                            __builtin_amdgcn_readlane(hi, 63));
                    int jr = BIG;
                    if (c1 == m) jr = 2 * lane + 2;
                    if (c0 == m) jr = 2 * lane + 1;
                    const unsigned long long brr = __ballot(jr != BIG);
                    const int jsel =
                        __builtin_amdgcn_readlane(jr, (int)__builtin_ctzll(brr));
                    if (lane == 0) { cmin_lds[rr] = m; cjmin_lds[rr] = jsel; }
                }
            }
        }
        __syncthreads();

        // ---- Pass B (R19 fix): merge every used col's NEW value into ALL
        // rows' cache. Handles v-increase cols (amt<0) that can steal any
        // row's argmin; provably a no-op for v-decrease cols; idempotent on
        // Pass-A rows (same fl(C-v) rounding). Lane owns rows lane+64g.
        if (nU > 0) {
            double cmr[4]; int cjr[4];
#pragma unroll
            for (int g = 0; g < 4; ++g) {
                cmr[g] = cmin_lds[lane + 64 * g];
                cjr[g] = cjmin_lds[lane + 64 * g];
            }
            unsigned long long m0 = __ballot((used & 1) != 0);
            unsigned long long m1 = __ballot((used & 2) != 0);
            while (m0) {
                const int ol = (int)__builtin_ctzll(m0); m0 &= m0 - 1;
                const int j = 2 * ol + 1;
                const double va = readlane_d(v0, ol);
#pragma unroll
                for (int g = 0; g < 4; ++g) {
                    const double cnd =
                        (double)C_lds[(lane + 64 * g) * K_ + (j - 1)] - va;
                    if (cnd < cmr[g] || (cnd == cmr[g] && j < cjr[g])) {
                        cmr[g] = cnd; cjr[g] = j;
                    }
                }
            }
            while (m1) {
                const int ol = (int)__builtin_ctzll(m1); m1 &= m1 - 1;
                const int j = 2 * ol + 2;
                const double va = readlane_d(v1, ol);
#pragma unroll
                for (int g = 0; g < 4; ++g) {
                    const double cnd =
                        (double)C_lds[(lane + 64 * g) * K_ + (j - 1)] - va;
                    if (cnd < cmr[g] || (cnd == cmr[g] && j < cjr[g])) {
                        cmr[g] = cnd; cjr[g] = j;
                    }
                }
            }
#pragma unroll
            for (int g = 0; g < 4; ++g) {
                cmin_lds[lane + 64 * g] = cmr[g];
                cjmin_lds[lane + 64 * g] = cjr[g];
            }
        }
        __syncthreads();
    }

    // out[b][k] = p[k+1] - 1 for the K real columns
    for (int j = lane; j < K_; j += 64)
        out[b * K_ + j] = p_lds[j + 1] - 1;
}

// ------------------------------------------------------------------- launcher
extern "C" void kernel_launch(void* const* d_in, const int* in_sizes, int n_in,
                              void* d_out, int out_size, void* d_ws, size_t ws_size,
                              hipStream_t stream) {
    const float* mp = (const float*)d_in[0];   // meta_points
    const float* mv = (const float*)d_in[1];   // meta_visibles
    /* d_in[2] covisibles: unused by reference */
    const float* gt = (const float*)d_in[3];   // gtpoints
    const float* gv = (const float*)d_in[4];   // gtvisibles
    int* out = (int*)d_out;                    // int32 assignment indices
    float* cost = (float*)d_ws;                // 16*256*128 fp32 = 2 MB

    dim3 gridA(B_, M_);
    cost_kernel<<<gridA, K_, 0, stream>>>(mp, mv, gt, gv, cost);
    match_kernel<<<B_, 64, 0, stream>>>(cost, out);
}

// Round 9
// 3837.099 us; speedup vs baseline: 1.3343x; 1.3343x over previous
//
#include <hip/hip_runtime.h>
#include <math.h>

// Problem: MPMatcher  S=6, B=16, L=8, M=256, K=128
// Phase 1 (PASSING, DO NOT TOUCH): cost f32, ocml logf, *(1/6) reciprocal mean.
// Phase 2: reference's buggy greedy walk. R20: structural collapse of the walk.
// Measured (R17): 1490 marches + 392 real-wins per block; ~1650 cy/iter in R15;
// R19 showed marches still pay a ladder (SELBEST) and cache fixup storms.
// R20 uses the u-cancellation identity: with duals frozen intra-walk, the
// march decision is  cmin[row] <= -v_dummy  (u cancels exactly). Hence:
//   - sort the 128 dummies once per walk (R12-proven bitonic, v desc / j asc);
//     intra-walk consumption is a PREFIX of the sorted list (R12-proven).
//   - march-stop flags are STATIC per walk: flag_t = cmin[row(S[t-1])]<=-v_S[t];
//     two ballots per walk; each run's length = first set flag (SALU masks).
//     Cached fm <= true free-min  =>  flags only over-stop (false stops),
//     corrected by the authoritative fl-exact verify; never under-stop.
//   - march deltas are mutually independent (delta_t = (0-u_snap[t-1])-v_t);
//     only the usum chain is serial (ref rounding order, ~18cy/step).
//   - ladders only at walk-start / post-real-step rows (~3/walk), u-free
//     contract fl(C-v) then fl(cm-u) (R19-proven regroup class, absmax 0).
//   - cache (cmin/cjmin over the 128 dummy rows only) rebuilt by a STAGGERED
//     column sweep (lane L reads col (it+L)&127 -> 2 lanes/bank, conflict-free)
//     only on walks that changed real-col v (nU>0). Kills R19's ladder storm.
//   - committed f64 formulas byte-identical to proven rounds: reals via Ua
//     (R15), dummies via Dcons prefix (R14), p/u commit (R11).

#define S_ 6
#define B_ 16
#define L_ 8
#define M_ 256
#define K_ 128

// ---------------------------------------------------------------- cost kernel
__global__ void cost_kernel(const float* __restrict__ mp,   // (6,16,8,256,2)
                            const float* __restrict__ mv,   // (6,16,256,1)
                            const float* __restrict__ gt,   // (6,16,128,2)
                            const float* __restrict__ gv,   // (6,16,128,1)
                            float* __restrict__ cost)       // (16,256,128)
{
#pragma clang fp contract(off)
    const int b = blockIdx.x;
    const int m = blockIdx.y;
    const int k = threadIdx.x;

    float accS = 0.0f;
    for (int s = 0; s < S_; ++s) {
        const int sb = s * B_ + b;
        const float gx = gt[(sb * K_ + k) * 2 + 0];
        const float gy = gt[(sb * K_ + k) * 2 + 1];
        float accL = 0.0f;
#pragma unroll
        for (int l = 0; l < L_; ++l) {
            const int base = ((sb * L_ + l) * M_ + m) * 2;
            const float dx = fabsf(mp[base + 0] - gx);
            const float dy = fabsf(mp[base + 1] - gy);
            const float diff = dx + dy;
            const float dl = (float)(L_ - (l + 1)) * 0.05f;
            const float t = diff - dl;
            accL += fmaxf(t, 0.0f);
        }
        const float meanL = accL * 0.125f;
        const float mvv = mv[sb * M_ + m];
        const float gtv = gv[sb * K_ + k];
        const float lp = -logf(mvv);
        const float ln = -logf(1.0f - mvv);
        const float val = (gtv != 0.0f) ? (5.0f * meanL + lp) : ln;
        accS += val;
    }
    cost[(b * M_ + m) * K_ + k] = accS * (1.0f / 6.0f);
}

// --------------------------------------------------------------- bit helpers
__device__ __forceinline__ double bits2d(int lo, int hi) {
    const unsigned long long u =
        ((unsigned long long)(unsigned)hi << 32) | (unsigned)lo;
    return __longlong_as_double((long long)u);
}
__device__ __forceinline__ void d2bits(double d, int& lo, int& hi) {
    const unsigned long long u = (unsigned long long)__double_as_longlong(d);
    lo = (int)(u & 0xffffffffull);
    hi = (int)(u >> 32);
}
__device__ __forceinline__ double readlane_d(double d, int l) {
    int lo, hi; d2bits(d, lo, hi);
    return bits2d(__builtin_amdgcn_readlane(lo, l),
                  __builtin_amdgcn_readlane(hi, l));
}
// ascending-sortable key for DESCENDING v (ties broken by j separately);
// canonicalizes -0 -> +0 (R12-proven)
__device__ __forceinline__ unsigned long long vkey_desc(double v) {
    const double c = v + 0.0;
    const unsigned long long bts = (unsigned long long)__double_as_longlong(c);
    const unsigned long long mask =
        (unsigned long long)((long long)bts >> 63) | 0x8000000000000000ull;
    return ~(bts ^ mask);
}

// one DPP reduction stage on a (lo,hi) f64 register pair with combiner FOP
#define RSTG(LOV, HIV, FOP, CTRL, RM)                                            \
    {                                                                            \
        const int nlo_ = __builtin_amdgcn_update_dpp(LOV, LOV, CTRL, RM, 0xf, false); \
        const int nhi_ = __builtin_amdgcn_update_dpp(HIV, HIV, CTRL, RM, 0xf, false); \
        const double r_ = FOP(bits2d(LOV, HIV), bits2d(nlo_, nhi_));             \
        d2bits(r_, LOV, HIV);                                                    \
    }
#define RLADDER(LOV, HIV, FOP)                                                   \
    RSTG(LOV, HIV, FOP, 0x111, 0xf)  /* row_shr:1  */                            \
    RSTG(LOV, HIV, FOP, 0x112, 0xf)  /* row_shr:2  */                            \
    RSTG(LOV, HIV, FOP, 0x114, 0xf)  /* row_shr:4  */                            \
    RSTG(LOV, HIV, FOP, 0x118, 0xf)  /* row_shr:8  */                            \
    RSTG(LOV, HIV, FOP, 0x142, 0xa)  /* row_bcast:15 -> rows 1,3 */              \
    RSTG(LOV, HIV, FOP, 0x143, 0xc)  /* row_bcast:31 -> rows 2,3 */

// exact free-min over real cols of row R0B (0-based): cm = min fl(C - v) with
// this walk's used real cols masked INF; cj = lowest-j argmin (1-based).
#define FREEMIN(R0B, CMV, CJV)                                                   \
    {                                                                            \
        double cd0_ = (double)C_lds[(R0B) * K_ + 2 * lane] - v0;                 \
        double cd1_ = (double)C_lds[(R0B) * K_ + 2 * lane + 1] - v1;             \
        if (used & 1) cd0_ = INF;                                                \
        if (used & 2) cd1_ = INF;                                                \
        double bv_ = fmin(cd0_, cd1_);                                           \
        int lo_, hi_; d2bits(bv_, lo_, hi_);                                     \
        RLADDER(lo_, hi_, fmin)                                                  \
        CMV = bits2d(__builtin_amdgcn_readlane(lo_, 63),                         \
                     __builtin_amdgcn_readlane(hi_, 63));                        \
        int jr_ = BIG;                                                           \
        if (cd1_ == CMV) jr_ = 2 * lane + 2;                                     \
        if (cd0_ == CMV) jr_ = 2 * lane + 1;                                     \
        const unsigned long long br_ = __ballot(jr_ != BIG);                     \
        CJV = __builtin_amdgcn_readlane(jr_, (int)__builtin_ctzll(br_));         \
    }

// staggered conflict-free rebuild of cmin/cjmin for the 128 dummy rows with
// current v_tab; tie rule (value, col) lexicographic -> order-independent
#define SWEEP()                                                                  \
    {                                                                            \
        for (int g_ = 0; g_ < 2; ++g_) {                                         \
            const int R_ = 64 * g_ + lane;                                       \
            double bm_ = INF; int bc_ = BIG;                                     \
            for (int it_ = 0; it_ < 128; ++it_) {                                \
                const int c_ = (it_ + lane) & 127;                               \
                const double cd_ = (double)C_lds[R_ * K_ + c_] - v_tab[c_];      \
                if (cd_ < bm_ || (cd_ == bm_ && c_ + 1 < bc_)) {                 \
                    bm_ = cd_; bc_ = c_ + 1;                                     \
                }                                                                \
            }                                                                    \
            cmin_lds[R_] = bm_; cjmin_lds[R_] = bc_;                             \
        }                                                                        \
    }

// wave-uniform reads from the sorted per-lane registers (position T = 2*lane+slot)
#define SVREAD(T) readlane_d((((T) & 1) ? sv1 : sv0), (T) >> 1)
#define SUREAD(T) readlane_d((((T) & 1) ? su1 : su0), (T) >> 1)
#define DDREAD(T) readlane_d((((T) & 1) ? dd1 : dd0), (T) >> 1)
#define JSREAD(T) __builtin_amdgcn_readlane(((((T) & 1)) ? js1 : js0), (T) >> 1)

// ------------------------------------------------------------- matcher kernel
// One wave per batch. Lane owns real cols j=2*lane+1, 2*lane+2 (slots 0,1).
__global__ __launch_bounds__(64, 1) void match_kernel(const float* __restrict__ cost,
                                                      int* __restrict__ out)
{
#pragma clang fp contract(off)
    const int b = blockIdx.x;
    const int lane = threadIdx.x;   // 0..63
    const float* C = cost + (size_t)b * M_ * K_;
    const double INF = __builtin_inf();
    const double NINF = -__builtin_inf();
    const int BIG = 0x7fffffff;

    __shared__ float  C_lds[M_ * K_];   // 128 KB cost slab
    __shared__ double u_lds[257];       // u[0..256], 1-based rows
    __shared__ int    p_lds[257];       // p[j]; 0 = free
    __shared__ double vd_lds[128];      // v of dummy cols 129..256
    __shared__ double v_tab[128];       // v of real cols 1..128 (mirror of v0/v1)
    __shared__ double cmin_lds[128];    // dummy-row cache: min fl(C[r]-v)
    __shared__ int    cjmin_lds[128];   // its lowest-j argmin (1-based)
    __shared__ double Sul[128];         // sorted u-snapshots (for neighbor read)
    __shared__ int    Sjl[128];         // sorted dummy col js
    __shared__ double Dcons[128];       // usum after consuming sorted slot t

    for (int t = lane; t < (M_ * K_) / 4; t += 64)
        ((float4*)C_lds)[t] = ((const float4*)C)[t];
    for (int t = lane; t < 257; t += 64) {
        u_lds[t] = 0.0;
        p_lds[t] = (t >= 129) ? (t - 128) : 0;   // rows 1..128 pre-matched (R8)
    }
    for (int t = lane; t < 128; t += 64) { vd_lds[t] = 0.0; v_tab[t] = 0.0; }
    __syncthreads();

    // cache init at v=0: fl(C-0) = C exactly
    SWEEP()
    __syncthreads();

    double v0 = 0.0, v1 = 0.0;   // real col potentials (persist across walks)

    for (int i = 129; i <= 256; ++i) {
        // ---- walk prologue: snapshots (valid: u/p/v written only at commit)
        const int pj0 = p_lds[2 * lane + 1];
        const int pj1 = p_lds[2 * lane + 2];
        const double up0 = u_lds[pj0], up1 = u_lds[pj1];

        // ---- bitonic sort of 128 dummies by (v desc, j asc)  [R12-proven]
        unsigned long long ks0 = vkey_desc(vd_lds[2 * lane]);
        unsigned long long ks1 = vkey_desc(vd_lds[2 * lane + 1]);
        int js0 = 2 * lane + 129;
        int js1 = 2 * lane + 130;
        for (int k = 2; k <= 128; k <<= 1) {
            const bool asc = ((lane & (k >> 1)) == 0);
            for (int d2 = k >> 1; d2 >= 1; d2 >>= 1) {
                if (d2 == 1) {
                    const bool Lc = (ks0 < ks1) || (ks0 == ks1 && js0 < js1);
                    if (Lc != asc) {
                        const unsigned long long tk = ks0; ks0 = ks1; ks1 = tk;
                        const int tj = js0; js0 = js1; js1 = tj;
                    }
                } else {
                    const int d = d2 >> 1;
                    const unsigned long long pk0 = __shfl_xor(ks0, d);
                    const int pj0s = __shfl_xor(js0, d);
                    const unsigned long long pk1 = __shfl_xor(ks1, d);
                    const int pj1s = __shfl_xor(js1, d);
                    const bool lower = ((lane & d) == 0);
                    const bool L0 = (ks0 < pk0) || (ks0 == pk0 && js0 < pj0s);
                    const bool L1 = (ks1 < pk1) || (ks1 == pk1 && js1 < pj1s);
                    const bool keep0 = (lower == asc) ? L0 : !L0;
                    const bool keep1 = (lower == asc) ? L1 : !L1;
                    if (!keep0) { ks0 = pk0; js0 = pj0s; }
                    if (!keep1) { ks1 = pk1; js1 = pj1s; }
                }
            }
        }
        // gather sorted (v, u-snapshot) into registers; publish for neighbors
        const double sv0 = vd_lds[js0 - 129], sv1 = vd_lds[js1 - 129];
        const double su0 = u_lds[js0 - 128],  su1 = u_lds[js1 - 128];
        Sul[2 * lane] = su0; Sul[2 * lane + 1] = su1;
        Sjl[2 * lane] = js0; Sjl[2 * lane + 1] = js1;
        __syncthreads();

        // static march deltas (independent: u_prev is a frozen snapshot) and
        // static stop flags (u-cancelled: cmin[row(S[t-1])] <= -v_S[t])
        const double supm = (lane > 0) ? Sul[2 * lane - 1] : 0.0;
        const double dd0 = (0.0 - supm) - sv0;   // delta for t=2l (l>=1 only)
        const double dd1 = (0.0 - su0) - sv1;    // delta for t=2l+1
        const int jprev = (lane > 0) ? Sjl[2 * lane - 1] : 129;
        const bool f0 = (lane > 0) && (cmin_lds[jprev - 129] <= -sv0);
        const bool f1 = (cmin_lds[js0 - 129] <= -sv1);
        const unsigned long long be = __ballot(f0);   // flags at even t
        const unsigned long long bo = __ballot(f1);   // flags at odd  t

        // ---- walk state
        double u = 0.0, usum = 0.0;
        int used = 0, nU = 0, j1 = 0, ptr = 0;
        int jU0 = 0, jU1 = 0, jU2 = 0, jU3 = 0;
        double Ua0 = 0.0, Ua1 = 0.0;
        int r0b = i - 1;                       // current row, 0-based (>=128)
        double cm; int cj;
        FREEMIN(r0b, cm, cj)                   // exact free-min (nothing used)

        for (;;) {
            // ---- run length: first stop position t* >= ptr
            int tstar;
            if (ptr >= 128) tstar = 128;
            else {
                const double svp = SVREAD(ptr);
                if (cm <= -svp) tstar = ptr;   // dynamic flag at t = ptr
                else {
                    const int she = (ptr >> 1) + 1;
                    const int sho = (ptr >> 1) + (ptr & 1);
                    const unsigned long long mbe =
                        (she < 64) ? (be & (~0ull << she)) : 0ull;
                    const unsigned long long mbo =
                        (sho < 64) ? (bo & (~0ull << sho)) : 0ull;
                    const int ea = mbe ? 2 * (int)__builtin_ctzll(mbe) : 256;
                    const int eb = mbo ? 2 * (int)__builtin_ctzll(mbo) + 1 : 256;
                    tstar = ea < eb ? ea : eb;
                    if (tstar > 128) tstar = 128;
                }
            }
            // ---- consume marches S[ptr..tstar-1]: serial usum chain only
            if (tstar > ptr) {
                const double svp2 = SVREAD(ptr);
                const double dfirst = (0.0 - u) - svp2;   // ref order, f64
                usum = usum + dfirst;
                if (lane == 0) Dcons[ptr] = usum;
                for (int k2 = ptr + 1; k2 < tstar; ++k2) {
                    const double dk = DDREAD(k2);
                    usum = usum + dk;
                    if (lane == 0) Dcons[k2] = usum;
                }
                u = SUREAD(tstar - 1);
                r0b = JSREAD(tstar - 1) - 129;
                ptr = tstar;
                cm = cmin_lds[r0b]; cj = cjmin_lds[r0b];
            }
            // ---- authoritative verify at row r0b vs head S[ptr]
            const double vh = (ptr < 128) ? SVREAD(ptr) : NINF;
            const double dval = (0.0 - u) - vh;           // +INF when exhausted
            double rmin; int rj;
            const bool fastok = (nU < 5) && (cj != jU0) && (cj != jU1)
                                         && (cj != jU2) && (cj != jU3);
            if (fastok) { rmin = cm - u; rj = cj; }       // R19-proven regroup
            else { double lm; int lj; FREEMIN(r0b, lm, lj) rmin = lm - u; rj = lj; }

            if (rmin <= dval) {
                // ---- real column wins (ref: real j < dummy j at ties)
                usum = usum + rmin;
                j1 = rj;
                const int ol = (j1 - 1) >> 1, sl = (j1 - 1) & 1;
                const int i0n = __builtin_amdgcn_readlane(sl ? pj1 : pj0, ol);
                if (i0n == 0) break;                      // augment
                const double un = readlane_d(sl ? up1 : up0, ol);
                if (lane == ol) {
                    used |= (1 << sl);
                    if (sl == 0) Ua0 = usum; else Ua1 = usum;
                }
                if (nU == 0) jU0 = j1; else if (nU == 1) jU1 = j1;
                else if (nU == 2) jU2 = j1; else if (nU == 3) jU3 = j1;
                ++nU;
                u = un;
                r0b = i0n - 1;                            // >=128: uncached
                FREEMIN(r0b, cm, cj)
            } else {
                // ---- false stop (cached fm was stale-low): march one, go on
                usum = usum + dval;
                if (lane == 0) Dcons[ptr] = usum;
                u = SUREAD(ptr);
                r0b = JSREAD(ptr) - 129;
                ++ptr;
                cm = cmin_lds[r0b]; cj = cjmin_lds[r0b];
            }
        }

        // ---- commit: deferred duals (R14/R15-proven formulas)
        __syncthreads();
        if (used & 1) { const double a = usum - Ua0; u_lds[pj0] = up0 + a;
                        v0 -= a; v_tab[2 * lane] = v0; }
        if (used & 2) { const double a = usum - Ua1; u_lds[pj1] = up1 + a;
                        v1 -= a; v_tab[2 * lane + 1] = v1; }
        if (2 * lane < ptr) {
            const double amt = usum - Dcons[2 * lane];
            u_lds[js0 - 128] += amt;
            vd_lds[js0 - 129] -= amt;
        }
        if (2 * lane + 1 < ptr) {
            const double amt = usum - Dcons[2 * lane + 1];
            u_lds[js1 - 128] += amt;
            vd_lds[js1 - 129] -= amt;
        }
        if (lane == 0) { p_lds[j1] = i; u_lds[i] = usum; }
        __syncthreads();

        // ---- cache rebuild only when real-col v changed this walk
        if (nU > 0) {
            SWEEP()
            __syncthreads();
        }
    }

    // out[b][k] = p[k+1] - 1 for the K real columns
    for (int j = lane; j < K_; j += 64)
        out[b * K_ + j] = p_lds[j + 1] - 1;
}

// ------------------------------------------------------------------- launcher
extern "C" void kernel_launch(void* const* d_in, const int* in_sizes, int n_in,
                              void* d_out, int out_size, void* d_ws, size_t ws_size,
                              hipStream_t stream) {
    const float* mp = (const float*)d_in[0];   // meta_points
    const float* mv = (const float*)d_in[1];   // meta_visibles
    /* d_in[2] covisibles: unused by reference */
    const float* gt = (const float*)d_in[3];   // gtpoints
    const float* gv = (const float*)d_in[4];   // gtvisibles
    int* out = (int*)d_out;                    // int32 assignment indices
    float* cost = (float*)d_ws;                // 16*256*128 fp32 = 2 MB

    dim3 gridA(B_, M_);
    cost_kernel<<<gridA, K_, 0, stream>>>(mp, mv, gt, gv, cost);
    match_kernel<<<B_, 64, 0, stream>>>(cost, out);
}

// Round 10
// 2177.881 us; speedup vs baseline: 2.3509x; 1.7618x over previous
//
#include <hip/hip_runtime.h>
#include <math.h>

// Problem: MPMatcher  S=6, B=16, L=8, M=256, K=128
// Phase 1 (PASSING, DO NOT TOUCH): cost f32, ocml logf, *(1/6) reciprocal mean.
// Phase 2: reference's buggy greedy walk. R21 = R20 (proven absmax 0) minus the
// per-walk SWEEP (measured dominant: ~25-30k cy/call at 1-wave effective cost
// ~10cy/instr -> ~1.25ms of R20's 3.8ms). Lazy stale-low cache instead:
//   INVARIANT: cmin_lds[r] <= fl(C[r][c]-v_c) for ALL real cols c (stale-LOW
//   allowed when a col's value rises), and if fresh, cjmin is the lowest-j
//   achiever. Maintained by:
//   (1) init: one SWEEP at v=0 (exact, runs once);
//   (2) commit: R19-PassB merge (proven) of each used col's NEW value into all
//       128 dummy rows -- restores the invariant for value-decreases exactly;
//       value-increases leave entries stale-low (flags only OVER-stop, safe);
//   (3) verify: O(1) re-validation -- re-read fl(C[r][cj]-v_cj); == cm means
//       fresh => cm is the true min, cj lowest-j (PassB tie rule) => R20's
//       proven fast path. Else FREEMIN + lazy repair (write-back iff nU==0).
// Everything else byte-identical to R20: bitonic sort (v desc, j asc), prefix
// consumption with static dd deltas + Dcons, static stop-flag ballots with
// u-cancellation, FREEMIN ladder, deferred-dual commit (R14/R15 formulas).

#define S_ 6
#define B_ 16
#define L_ 8
#define M_ 256
#define K_ 128

// ---------------------------------------------------------------- cost kernel
__global__ void cost_kernel(const float* __restrict__ mp,   // (6,16,8,256,2)
                            const float* __restrict__ mv,   // (6,16,256,1)
                            const float* __restrict__ gt,   // (6,16,128,2)
                            const float* __restrict__ gv,   // (6,16,128,1)
                            float* __restrict__ cost)       // (16,256,128)
{
#pragma clang fp contract(off)
    const int b = blockIdx.x;
    const int m = blockIdx.y;
    const int k = threadIdx.x;

    float accS = 0.0f;
    for (int s = 0; s < S_; ++s) {
        const int sb = s * B_ + b;
        const float gx = gt[(sb * K_ + k) * 2 + 0];
        const float gy = gt[(sb * K_ + k) * 2 + 1];
        float accL = 0.0f;
#pragma unroll
        for (int l = 0; l < L_; ++l) {
            const int base = ((sb * L_ + l) * M_ + m) * 2;
            const float dx = fabsf(mp[base + 0] - gx);
            const float dy = fabsf(mp[base + 1] - gy);
            const float diff = dx + dy;
            const float dl = (float)(L_ - (l + 1)) * 0.05f;
            const float t = diff - dl;
            accL += fmaxf(t, 0.0f);
        }
        const float meanL = accL * 0.125f;
        const float mvv = mv[sb * M_ + m];
        const float gtv = gv[sb * K_ + k];
        const float lp = -logf(mvv);
        const float ln = -logf(1.0f - mvv);
        const float val = (gtv != 0.0f) ? (5.0f * meanL + lp) : ln;
        accS += val;
    }
    cost[(b * M_ + m) * K_ + k] = accS * (1.0f / 6.0f);
}

// --------------------------------------------------------------- bit helpers
__device__ __forceinline__ double bits2d(int lo, int hi) {
    const unsigned long long u =
        ((unsigned long long)(unsigned)hi << 32) | (unsigned)lo;
    return __longlong_as_double((long long)u);
}
__device__ __forceinline__ void d2bits(double d, int& lo, int& hi) {
    const unsigned long long u = (unsigned long long)__double_as_longlong(d);
    lo = (int)(u & 0xffffffffull);
    hi = (int)(u >> 32);
}
__device__ __forceinline__ double readlane_d(double d, int l) {
    int lo, hi; d2bits(d, lo, hi);
    return bits2d(__builtin_amdgcn_readlane(lo, l),
                  __builtin_amdgcn_readlane(hi, l));
}
// ascending-sortable key for DESCENDING v (ties broken by j separately);
// canonicalizes -0 -> +0 (R12-proven)
__device__ __forceinline__ unsigned long long vkey_desc(double v) {
    const double c = v + 0.0;
    const unsigned long long bts = (unsigned long long)__double_as_longlong(c);
    const unsigned long long mask =
        (unsigned long long)((long long)bts >> 63) | 0x8000000000000000ull;
    return ~(bts ^ mask);
}

// one DPP reduction stage on a (lo,hi) f64 register pair with combiner FOP
#define RSTG(LOV, HIV, FOP, CTRL, RM)                                            \
    {                                                                            \
        const int nlo_ = __builtin_amdgcn_update_dpp(LOV, LOV, CTRL, RM, 0xf, false); \
        const int nhi_ = __builtin_amdgcn_update_dpp(HIV, HIV, CTRL, RM, 0xf, false); \
        const double r_ = FOP(bits2d(LOV, HIV), bits2d(nlo_, nhi_));             \
        d2bits(r_, LOV, HIV);                                                    \
    }
#define RLADDER(LOV, HIV, FOP)                                                   \
    RSTG(LOV, HIV, FOP, 0x111, 0xf)  /* row_shr:1  */                            \
    RSTG(LOV, HIV, FOP, 0x112, 0xf)  /* row_shr:2  */                            \
    RSTG(LOV, HIV, FOP, 0x114, 0xf)  /* row_shr:4  */                            \
    RSTG(LOV, HIV, FOP, 0x118, 0xf)  /* row_shr:8  */                            \
    RSTG(LOV, HIV, FOP, 0x142, 0xa)  /* row_bcast:15 -> rows 1,3 */              \
    RSTG(LOV, HIV, FOP, 0x143, 0xc)  /* row_bcast:31 -> rows 2,3 */

// exact free-min over real cols of row R0B (0-based): cm = min fl(C - v) with
// this walk's used real cols masked INF; cj = lowest-j argmin (1-based).
#define FREEMIN(R0B, CMV, CJV)                                                   \
    {                                                                            \
        double cd0_ = (double)C_lds[(R0B) * K_ + 2 * lane] - v0;                 \
        double cd1_ = (double)C_lds[(R0B) * K_ + 2 * lane + 1] - v1;             \
        if (used & 1) cd0_ = INF;                                                \
        if (used & 2) cd1_ = INF;                                                \
        double bv_ = fmin(cd0_, cd1_);                                           \
        int lo_, hi_; d2bits(bv_, lo_, hi_);                                     \
        RLADDER(lo_, hi_, fmin)                                                  \
        CMV = bits2d(__builtin_amdgcn_readlane(lo_, 63),                         \
                     __builtin_amdgcn_readlane(hi_, 63));                        \
        int jr_ = BIG;                                                           \
        if (cd1_ == CMV) jr_ = 2 * lane + 2;                                     \
        if (cd0_ == CMV) jr_ = 2 * lane + 1;                                     \
        const unsigned long long br_ = __ballot(jr_ != BIG);                     \
        CJV = __builtin_amdgcn_readlane(jr_, (int)__builtin_ctzll(br_));         \
    }

// staggered conflict-free build of cmin/cjmin for the 128 dummy rows with
// current v_tab; tie rule (value, col) lexicographic. INIT ONLY in R21.
#define SWEEP()                                                                  \
    {                                                                            \
        for (int g_ = 0; g_ < 2; ++g_) {                                         \
            const int R_ = 64 * g_ + lane;                                       \
            double bm_ = INF; int bc_ = BIG;                                     \
            for (int it_ = 0; it_ < 128; ++it_) {                                \
                const int c_ = (it_ + lane) & 127;                               \
                const double cd_ = (double)C_lds[R_ * K_ + c_] - v_tab[c_];      \
                if (cd_ < bm_ || (cd_ == bm_ && c_ + 1 < bc_)) {                 \
                    bm_ = cd_; bc_ = c_ + 1;                                     \
                }                                                                \
            }                                                                    \
            cmin_lds[R_] = bm_; cjmin_lds[R_] = bc_;                             \
        }                                                                        \
    }

// wave-uniform reads from the sorted per-lane registers (position T = 2*lane+slot)
#define SVREAD(T) readlane_d((((T) & 1) ? sv1 : sv0), (T) >> 1)
#define SUREAD(T) readlane_d((((T) & 1) ? su1 : su0), (T) >> 1)
#define DDREAD(T) readlane_d((((T) & 1) ? dd1 : dd0), (T) >> 1)
#define JSREAD(T) __builtin_amdgcn_readlane(((((T) & 1)) ? js1 : js0), (T) >> 1)

// ------------------------------------------------------------- matcher kernel
// One wave per batch. Lane owns real cols j=2*lane+1, 2*lane+2 (slots 0,1).
__global__ __launch_bounds__(64, 1) void match_kernel(const float* __restrict__ cost,
                                                      int* __restrict__ out)
{
#pragma clang fp contract(off)
    const int b = blockIdx.x;
    const int lane = threadIdx.x;   // 0..63
    const float* C = cost + (size_t)b * M_ * K_;
    const double INF = __builtin_inf();
    const double NINF = -__builtin_inf();
    const int BIG = 0x7fffffff;

    __shared__ float  C_lds[M_ * K_];   // 128 KB cost slab
    __shared__ double u_lds[257];       // u[0..256], 1-based rows
    __shared__ int    p_lds[257];       // p[j]; 0 = free
    __shared__ double vd_lds[128];      // v of dummy cols 129..256
    __shared__ double v_tab[128];       // v of real cols 1..128 (mirror of v0/v1)
    __shared__ double cmin_lds[128];    // dummy-row cache: min fl(C[r]-v), stale-low
    __shared__ int    cjmin_lds[128];   // its lowest-j argmin when fresh (1-based)
    __shared__ double Sul[128];         // sorted u-snapshots (for neighbor read)
    __shared__ int    Sjl[128];         // sorted dummy col js
    __shared__ double Dcons[128];       // usum after consuming sorted slot t

    for (int t = lane; t < (M_ * K_) / 4; t += 64)
        ((float4*)C_lds)[t] = ((const float4*)C)[t];
    for (int t = lane; t < 257; t += 64) {
        u_lds[t] = 0.0;
        p_lds[t] = (t >= 129) ? (t - 128) : 0;   // rows 1..128 pre-matched (R8)
    }
    for (int t = lane; t < 128; t += 64) { vd_lds[t] = 0.0; v_tab[t] = 0.0; }
    __syncthreads();

    // cache init at v=0: fl(C-0) = C exactly; runs ONCE (R21)
    SWEEP()
    __syncthreads();

    double v0 = 0.0, v1 = 0.0;   // real col potentials (persist across walks)

    for (int i = 129; i <= 256; ++i) {
        // ---- walk prologue: snapshots (valid: u/p/v written only at commit)
        const int pj0 = p_lds[2 * lane + 1];
        const int pj1 = p_lds[2 * lane + 2];
        const double up0 = u_lds[pj0], up1 = u_lds[pj1];

        // ---- bitonic sort of 128 dummies by (v desc, j asc)  [R12-proven]
        unsigned long long ks0 = vkey_desc(vd_lds[2 * lane]);
        unsigned long long ks1 = vkey_desc(vd_lds[2 * lane + 1]);
        int js0 = 2 * lane + 129;
        int js1 = 2 * lane + 130;
        for (int k = 2; k <= 128; k <<= 1) {
            const bool asc = ((lane & (k >> 1)) == 0);
            for (int d2 = k >> 1; d2 >= 1; d2 >>= 1) {
                if (d2 == 1) {
                    const bool Lc = (ks0 < ks1) || (ks0 == ks1 && js0 < js1);
                    if (Lc != asc) {
                        const unsigned long long tk = ks0; ks0 = ks1; ks1 = tk;
                        const int tj = js0; js0 = js1; js1 = tj;
                    }
                } else {
                    const int d = d2 >> 1;
                    const unsigned long long pk0 = __shfl_xor(ks0, d);
                    const int pj0s = __shfl_xor(js0, d);
                    const unsigned long long pk1 = __shfl_xor(ks1, d);
                    const int pj1s = __shfl_xor(js1, d);
                    const bool lower = ((lane & d) == 0);
                    const bool L0 = (ks0 < pk0) || (ks0 == pk0 && js0 < pj0s);
                    const bool L1 = (ks1 < pk1) || (ks1 == pk1 && js1 < pj1s);
                    const bool keep0 = (lower == asc) ? L0 : !L0;
                    const bool keep1 = (lower == asc) ? L1 : !L1;
                    if (!keep0) { ks0 = pk0; js0 = pj0s; }
                    if (!keep1) { ks1 = pk1; js1 = pj1s; }
                }
            }
        }
        // gather sorted (v, u-snapshot) into registers; publish for neighbors
        const double sv0 = vd_lds[js0 - 129], sv1 = vd_lds[js1 - 129];
        const double su0 = u_lds[js0 - 128],  su1 = u_lds[js1 - 128];
        Sul[2 * lane] = su0; Sul[2 * lane + 1] = su1;
        Sjl[2 * lane] = js0; Sjl[2 * lane + 1] = js1;
        __syncthreads();

        // static march deltas (independent: u_prev is a frozen snapshot) and
        // static stop flags (u-cancelled: cmin[row(S[t-1])] <= -v_S[t]);
        // stale-LOW cmin only adds flags (over-stop, verified) -- never misses
        const double supm = (lane > 0) ? Sul[2 * lane - 1] : 0.0;
        const double dd0 = (0.0 - supm) - sv0;   // delta for t=2l (l>=1 only)
        const double dd1 = (0.0 - su0) - sv1;    // delta for t=2l+1
        const int jprev = (lane > 0) ? Sjl[2 * lane - 1] : 129;
        const bool f0 = (lane > 0) && (cmin_lds[jprev - 129] <= -sv0);
        const bool f1 = (cmin_lds[js0 - 129] <= -sv1);
        const unsigned long long be = __ballot(f0);   // flags at even t
        const unsigned long long bo = __ballot(f1);   // flags at odd  t

        // ---- walk state
        double u = 0.0, usum = 0.0;
        int used = 0, nU = 0, j1 = 0, ptr = 0;
        int jU0 = 0, jU1 = 0, jU2 = 0, jU3 = 0;
        double Ua0 = 0.0, Ua1 = 0.0;
        int r0b = i - 1;                       // current row, 0-based (>=128)
        double cm; int cj;
        FREEMIN(r0b, cm, cj)                   // exact free-min (nothing used)

        for (;;) {
            // ---- run length: first stop position t* >= ptr
            int tstar;
            if (ptr >= 128) tstar = 128;
            else {
                const double svp = SVREAD(ptr);
                if (cm <= -svp) tstar = ptr;   // dynamic flag at t = ptr
                else {
                    const int she = (ptr >> 1) + 1;
                    const int sho = (ptr >> 1) + (ptr & 1);
                    const unsigned long long mbe =
                        (she < 64) ? (be & (~0ull << she)) : 0ull;
                    const unsigned long long mbo =
                        (sho < 64) ? (bo & (~0ull << sho)) : 0ull;
                    const int ea = mbe ? 2 * (int)__builtin_ctzll(mbe) : 256;
                    const int eb = mbo ? 2 * (int)__builtin_ctzll(mbo) + 1 : 256;
                    tstar = ea < eb ? ea : eb;
                    if (tstar > 128) tstar = 128;
                }
            }
            // ---- consume marches S[ptr..tstar-1]: serial usum chain only
            if (tstar > ptr) {
                const double svp2 = SVREAD(ptr);
                const double dfirst = (0.0 - u) - svp2;   // ref order, f64
                usum = usum + dfirst;
                if (lane == 0) Dcons[ptr] = usum;
                for (int k2 = ptr + 1; k2 < tstar; ++k2) {
                    const double dk = DDREAD(k2);
                    usum = usum + dk;
                    if (lane == 0) Dcons[k2] = usum;
                }
                u = SUREAD(tstar - 1);
                r0b = JSREAD(tstar - 1) - 129;
                ptr = tstar;
                cm = cmin_lds[r0b]; cj = cjmin_lds[r0b];
            }
            // ---- authoritative verify at row r0b vs head S[ptr]
            const double vh = (ptr < 128) ? SVREAD(ptr) : NINF;
            const double dval = (0.0 - u) - vh;           // +INF when exhausted
            double rmin; int rj;
            // O(1) re-validation: fresh cache entry == true min + lowest-j
            bool fast = false;
            if (r0b < 128 && nU < 5 && (cj != jU0) && (cj != jU1)
                                    && (cj != jU2) && (cj != jU3)) {
                const double x = (double)C_lds[r0b * K_ + (cj - 1)]
                               - v_tab[cj - 1];
                fast = (x == cm);
            }
            if (fast) { rmin = cm - u; rj = cj; }         // R20-proven regroup
            else {
                double lm; int lj;
                FREEMIN(r0b, lm, lj)
                rmin = lm - u; rj = lj;
                // lazy repair: only when masked-min == unmasked-min (nU==0)
                if (r0b < 128 && nU == 0 && lane == 0) {
                    cmin_lds[r0b] = lm; cjmin_lds[r0b] = lj;
                }
            }

            if (rmin <= dval) {
                // ---- real column wins (ref: real j < dummy j at ties)
                usum = usum + rmin;
                j1 = rj;
                const int ol = (j1 - 1) >> 1, sl = (j1 - 1) & 1;
                const int i0n = __builtin_amdgcn_readlane(sl ? pj1 : pj0, ol);
                if (i0n == 0) break;                      // augment
                const double un = readlane_d(sl ? up1 : up0, ol);
                if (lane == ol) {
                    used |= (1 << sl);
                    if (sl == 0) Ua0 = usum; else Ua1 = usum;
                }
                if (nU == 0) jU0 = j1; else if (nU == 1) jU1 = j1;
                else if (nU == 2) jU2 = j1; else if (nU == 3) jU3 = j1;
                ++nU;
                u = un;
                r0b = i0n - 1;                            // >=128: uncached
                FREEMIN(r0b, cm, cj)
            } else {
                // ---- false stop (stale-low or ulp): march one, continue
                usum = usum + dval;
                if (lane == 0) Dcons[ptr] = usum;
                u = SUREAD(ptr);
                r0b = JSREAD(ptr) - 129;
                ++ptr;
                cm = cmin_lds[r0b]; cj = cjmin_lds[r0b];
            }
        }

        // ---- commit: deferred duals (R14/R15-proven formulas)
        __syncthreads();
        if (used & 1) { const double a = usum - Ua0; u_lds[pj0] = up0 + a;
                        v0 -= a; v_tab[2 * lane] = v0; }
        if (used & 2) { const double a = usum - Ua1; u_lds[pj1] = up1 + a;
                        v1 -= a; v_tab[2 * lane + 1] = v1; }
        if (2 * lane < ptr) {
            const double amt = usum - Dcons[2 * lane];
            u_lds[js0 - 128] += amt;
            vd_lds[js0 - 129] -= amt;
        }
        if (2 * lane + 1 < ptr) {
            const double amt = usum - Dcons[2 * lane + 1];
            u_lds[js1 - 128] += amt;
            vd_lds[js1 - 129] -= amt;
        }
        if (lane == 0) { p_lds[j1] = i; u_lds[i] = usum; }
        __syncthreads();

        // ---- R19-PassB merge (proven): fold used cols' NEW values into the
        // dummy-row cache. Restores the stale-low invariant for decreases;
        // increases leave stale-low entries (caught by re-validation).
        if (nU > 0) {
            double cmr0 = cmin_lds[lane],      cmr1 = cmin_lds[lane + 64];
            int    cjr0 = cjmin_lds[lane],     cjr1 = cjmin_lds[lane + 64];
            unsigned long long m0 = __ballot((used & 1) != 0);
            unsigned long long m1 = __ballot((used & 2) != 0);
            while (m0) {
                const int ol = (int)__builtin_ctzll(m0); m0 &= m0 - 1;
                const int j = 2 * ol + 1;
                const double va = readlane_d(v0, ol);
                const double c0 = (double)C_lds[lane * K_ + (j - 1)] - va;
                const double c1 = (double)C_lds[(lane + 64) * K_ + (j - 1)] - va;
                if (c0 < cmr0 || (c0 == cmr0 && j < cjr0)) { cmr0 = c0; cjr0 = j; }
                if (c1 < cmr1 || (c1 == cmr1 && j < cjr1)) { cmr1 = c1; cjr1 = j; }
            }
            while (m1) {
                const int ol = (int)__builtin_ctzll(m1); m1 &= m1 - 1;
                const int j = 2 * ol + 2;
                const double va = readlane_d(v1, ol);
                const double c0 = (double)C_lds[lane * K_ + (j - 1)] - va;
                const double c1 = (double)C_lds[(lane + 64) * K_ + (j - 1)] - va;
                if (c0 < cmr0 || (c0 == cmr0 && j < cjr0)) { cmr0 = c0; cjr0 = j; }
                if (c1 < cmr1 || (c1 == cmr1 && j < cjr1)) { cmr1 = c1; cjr1 = j; }
            }
            cmin_lds[lane] = cmr0;      cjmin_lds[lane] = cjr0;
            cmin_lds[lane + 64] = cmr1; cjmin_lds[lane + 64] = cjr1;
            __syncthreads();
        }
    }

    // out[b][k] = p[k+1] - 1 for the K real columns
    for (int j = lane; j < K_; j += 64)
        out[b * K_ + j] = p_lds[j + 1] - 1;
}

// ------------------------------------------------------------------- launcher
extern "C" void kernel_launch(void* const* d_in, const int* in_sizes, int n_in,
                              void* d_out, int out_size, void* d_ws, size_t ws_size,
                              hipStream_t stream) {
    const float* mp = (const float*)d_in[0];   // meta_points
    const float* mv = (const float*)d_in[1];   // meta_visibles
    /* d_in[2] covisibles: unused by reference */
    const float* gt = (const float*)d_in[3];   // gtpoints
    const float* gv = (const float*)d_in[4];   // gtvisibles
    int* out = (int*)d_out;                    // int32 assignment indices
    float* cost = (float*)d_ws;                // 16*256*128 fp32 = 2 MB

    dim3 gridA(B_, M_);
    cost_kernel<<<gridA, K_, 0, stream>>>(mp, mv, gt, gv, cost);
    match_kernel<<<B_, 64, 0, stream>>>(cost, out);
}

// Round 11
// 2104.071 us; speedup vs baseline: 2.4334x; 1.0351x over previous
//
#include <hip/hip_runtime.h>
#include <math.h>

// Problem: MPMatcher  S=6, B=16, L=8, M=256, K=128
// Phase 1 (PASSING, DO NOT TOUCH): cost f32, ocml logf, *(1/6) reciprocal mean.
// Phase 2: reference's buggy greedy walk, f64-exact. R22 = R15 (best proven:
// 1297us, absmax 0) + carried-(key,j) DPP ladder:
//   - structural rewrites R19/R20/R21 (cache/sort/flags) all measured SLOWER
//     than R15's straight-line loop (2178-5120 vs 1297): per-walk machinery
//     (bpermute sort, gathers, stale-cache repair) costs more than it saves
//     at 1 wave/CU. Reverted.
//   - R22 cuts R15's chain tail: cd -> sortable u64 key (sign-magnitude
//     transform; EXACT total order for finite doubles; cds are never -0 here
//     because all costs > 0, so canonicalization is a no-op) and carries j
//     through the 6-stage ladder with lexicographic (key, j) min. Lane 63
//     ends with delta AND j1: the whole extraction block (4 f64 compares,
//     jr/jd selects, 2 ballots, ctz, readlane) is deleted; j1 is available
//     ~120-150cy earlier for the i0n/row-load chain; delta is recovered by a
//     4-op scalar inverse transform off the critical path.
//   - tie rule preserved exactly: local 4-way min via <= selects (tie ->
//     lowest slot = lowest j); ladder tie -> lowest j. Identical winner and
//     identical delta bits to R15's fmin+equality-extraction (bitwise ties
//     only, since distinct finite doubles have distinct bits and -0 is
//     impossible).
// R15 core (unchanged): fully-deferred dual updates (amt = usum_final - U_j
// at commit), software-pipelined speculative row load, rows 1..128
// pre-matched, dummies never re-matched (i0n = j1-128 statically).

#define S_ 6
#define B_ 16
#define L_ 8
#define M_ 256
#define K_ 128

// ---------------------------------------------------------------- cost kernel
__global__ void cost_kernel(const float* __restrict__ mp,   // (6,16,8,256,2)
                            const float* __restrict__ mv,   // (6,16,256,1)
                            const float* __restrict__ gt,   // (6,16,128,2)
                            const float* __restrict__ gv,   // (6,16,128,1)
                            float* __restrict__ cost)       // (16,256,128)
{
#pragma clang fp contract(off)
    const int b = blockIdx.x;
    const int m = blockIdx.y;
    const int k = threadIdx.x;

    float accS = 0.0f;
    for (int s = 0; s < S_; ++s) {
        const int sb = s * B_ + b;
        const float gx = gt[(sb * K_ + k) * 2 + 0];
        const float gy = gt[(sb * K_ + k) * 2 + 1];
        float accL = 0.0f;
#pragma unroll
        for (int l = 0; l < L_; ++l) {
            const int base = ((sb * L_ + l) * M_ + m) * 2;
            const float dx = fabsf(mp[base + 0] - gx);
            const float dy = fabsf(mp[base + 1] - gy);
            const float diff = dx + dy;
            const float dl = (float)(L_ - (l + 1)) * 0.05f;
            const float t = diff - dl;
            accL += fmaxf(t, 0.0f);
        }
        const float meanL = accL * 0.125f;
        const float mvv = mv[sb * M_ + m];
        const float gtv = gv[sb * K_ + k];
        const float lp = -logf(mvv);
        const float ln = -logf(1.0f - mvv);
        const float val = (gtv != 0.0f) ? (5.0f * meanL + lp) : ln;
        accS += val;
    }
    cost[(b * M_ + m) * K_ + k] = accS * (1.0f / 6.0f);
}

// --------------------------------------------------------------- bit helpers
__device__ __forceinline__ double bits2d(int lo, int hi) {
    const unsigned long long u =
        ((unsigned long long)(unsigned)hi << 32) | (unsigned)lo;
    return __longlong_as_double((long long)u);
}
__device__ __forceinline__ void d2bits(double d, int& lo, int& hi) {
    const unsigned long long u = (unsigned long long)__double_as_longlong(d);
    lo = (int)(u & 0xffffffffull);
    hi = (int)(u >> 32);
}

// ------------------------------------------------------------- matcher kernel
// One wave per batch. Lane owns real cols j=2*lane+1, 2*lane+2 (slots 0,1)
// and dummy cols j=2*lane+129, 2*lane+130 (slots 2,3).
__global__ __launch_bounds__(64, 1) void match_kernel(const float* __restrict__ cost,
                                                      int* __restrict__ out)
{
#pragma clang fp contract(off)
    const int b = blockIdx.x;
    const int lane = threadIdx.x;   // 0..63
    const float* C = cost + (size_t)b * M_ * K_;
    const double INF = __builtin_inf();

    __shared__ float  C_lds[M_ * K_];   // 128 KB cost slab (row-major, = global)
    __shared__ double u_lds[257];       // u[0..256], 1-based rows
    __shared__ int    p_lds[257];       // p[j] = row matched to col j; 0 = free

    // stage the batch's cost slab into LDS (coalesced float4 copies)
    for (int t = lane; t < (M_ * K_) / 4; t += 64)
        ((float4*)C_lds)[t] = ((const float4*)C)[t];

    // rows 1..128 pre-matched to dummy cols 129..256 (exact, proven R8)
    for (int t = lane; t < 257; t += 64) {
        u_lds[t] = 0.0;
        p_lds[t] = (t >= 129) ? (t - 128) : 0;
    }
    __syncthreads();

    double v0 = 0.0, v1 = 0.0, v2 = 0.0, v3 = 0.0;  // column potentials

    for (int i = 129; i <= 256; ++i) {
        // ---- row start: snapshot caches. p static during walk; dummies never
        // re-matched (p[dummy j] = j-128 statically); u[p[j]] for free cols
        // never updated mid-walk -> snapshots valid for broadcasts.
        const int pj0 = p_lds[2 * lane + 1];
        const int pj1 = p_lds[2 * lane + 2];
        const double up0 = u_lds[pj0], up1 = u_lds[pj1];
        const double up2 = u_lds[2 * lane + 1];   // p[2*lane+129] = 2*lane+1
        const double up3 = u_lds[2 * lane + 2];   // p[2*lane+130] = 2*lane+2

        float2 cc = *(const float2*)(C_lds + (i - 1) * K_ + 2 * lane);
        double u_i0 = 0.0;
        int used = 0;
        int j1 = 0;
        double usum = 0.0;
        // usum snapshot at choice time for each owned slot (valid iff used bit)
        double Ua0 = 0.0, Ua1 = 0.0, Ua2 = 0.0, Ua3 = 0.0;

        for (;;) {
            // candidates: cur = (cost - u[i0]) - v   (exact ref op order, f64)
            double cd0 = ((double)cc.x - u_i0) - v0;
            double cd1 = ((double)cc.y - u_i0) - v1;
            double cd2 = (0.0 - u_i0) - v2;
            double cd3 = (0.0 - u_i0) - v3;
            if (used & 1) cd0 = INF;
            if (used & 2) cd1 = INF;
            if (used & 4) cd2 = INF;
            if (used & 8) cd3 = INF;

            // local lexicographic (value, j) min; <= picks the lower j on ties
            // (slot j order: 2l+1 < 2l+2 < 2l+129 < 2l+130). cds are never -0
            // (all costs > 0), so ties are bitwise-equal only.
            const bool tA = (cd0 <= cd1);
            const double mA = tA ? cd0 : cd1;
            const int    jA = tA ? (2 * lane + 1) : (2 * lane + 2);
            const bool tB = (cd2 <= cd3);
            const double mB = tB ? cd2 : cd3;
            const int    jB = tB ? (2 * lane + 129) : (2 * lane + 130);
            const bool tC = (mA <= mB);          // real js < dummy js always
            const double bv = tC ? mA : mB;
            int jv = tC ? jA : jB;

            // sortable u64 key: ascending key order == ascending double order
            int lo, hi; d2bits(bv, lo, hi);
            const int sgn = hi >> 31;                    // 0 or -1
            int kh = hi ^ (sgn | (int)0x80000000);
            int kl = lo ^ sgn;

            // 6-stage carried-(key, j) DPP ladder; lex min lands in lane 63.
            // Self-fallback lanes self-tie (harmless); duplicates harmless.
#define KSTG(CTRL, RM)                                                           \
            {                                                                    \
                const int nkl = __builtin_amdgcn_update_dpp(kl, kl, CTRL, RM, 0xf, false); \
                const int nkh = __builtin_amdgcn_update_dpp(kh, kh, CTRL, RM, 0xf, false); \
                const int njv = __builtin_amdgcn_update_dpp(jv, jv, CTRL, RM, 0xf, false); \
                const unsigned long long nk =                                    \
                    ((unsigned long long)(unsigned)nkh << 32) | (unsigned)nkl;   \
                const unsigned long long ok =                                    \
                    ((unsigned long long)(unsigned)kh << 32) | (unsigned)kl;     \
                const bool take = (nk < ok) || (nk == ok && njv < jv);           \
                if (take) { kl = nkl; kh = nkh; jv = njv; }                      \
            }
            KSTG(0x111, 0xf)   // row_shr:1
            KSTG(0x112, 0xf)   // row_shr:2
            KSTG(0x114, 0xf)   // row_shr:4
            KSTG(0x118, 0xf)   // row_shr:8
            KSTG(0x142, 0xa)   // row_bcast:15 -> rows 1,3
            KSTG(0x143, 0xc)   // row_bcast:31 -> rows 2,3
#undef KSTG
            // winner: j first (feeds the i0n/row-load chain), delta recovered
            // by scalar inverse transform off the chain
            j1 = __builtin_amdgcn_readlane(jv, 63);
            const int mkl = __builtin_amdgcn_readlane(kl, 63);
            const int mkh = __builtin_amdgcn_readlane(kh, 63);

            // next row: dummies are never re-matched -> p[j1] = j1-128 statically
            int ol, sl;
            if (j1 >= 129) { ol = (j1 - 129) >> 1; sl = 2 + ((j1 - 129) & 1); }
            else           { ol = (j1 - 1) >> 1;   sl = (j1 - 1) & 1; }
            const int psel = (sl == 0) ? pj0 : (sl == 1) ? pj1 : 0;
            const int i0n = (j1 >= 129) ? (j1 - 128)
                                        : __builtin_amdgcn_readlane(psel, ol);

            // speculative next-row load, issued ASAP (clamped; unused on break)
            const int rown = (i0n > 0 ? i0n : 1) - 1;
            const float2 ccn = *(const float2*)(C_lds + rown * K_ + 2 * lane);

            // ---- shadow work (under the load's latency) ----
            // inverse key transform -> delta (exact bits of the winning cd)
            const int dsg = mkh >> 31;            // -1 if original >= 0
            const int dhi = mkh ^ ((~dsg) | (int)0x80000000);
            const int dlo = mkl ^ (~dsg);
            const double delta = bits2d(dlo, dhi);
            usum += delta;

            // u[p[j1]] broadcast from owner's row-start snapshot
            const double usel = (sl == 0) ? up0 : (sl == 1) ? up1
                              : (sl == 2) ? up2 : up3;
            int ulo, uhi; d2bits(usel, ulo, uhi);
            const double u_n = bits2d(__builtin_amdgcn_readlane(ulo, ol),
                                      __builtin_amdgcn_readlane(uhi, ol));

            if (i0n == 0) break;    // free real column -> augment (way==0)

            // mark j1 used (it is j0 of the next iteration, ref marks at top)
            // and snapshot the running sum for the deferred update
            if (lane == ol) {
                used |= (1 << sl);
                if (sl == 0)      Ua0 = usum;
                else if (sl == 1) Ua1 = usum;
                else if (sl == 2) Ua2 = usum;
                else              Ua3 = usum;
            }
            u_i0 = u_n;
            cc = ccn;
        }

        // ---- commit: deferred dual updates. Column j chosen at snapshot U_j
        // accumulates amt = usum_final - U_j (== sum of all later deltas).
        // Distinct columns -> distinct rows -> no LDS write conflicts.
        __syncthreads();
        if (used & 1) { const double a = usum - Ua0; u_lds[pj0] = up0 + a; v0 -= a; }
        if (used & 2) { const double a = usum - Ua1; u_lds[pj1] = up1 + a; v1 -= a; }
        if (used & 4) { const double a = usum - Ua2; u_lds[2 * lane + 1] = up2 + a; v2 -= a; }
        if (used & 8) { const double a = usum - Ua3; u_lds[2 * lane + 2] = up3 + a; v3 -= a; }
        if (lane == 0) { p_lds[j1] = i; u_lds[i] = usum; }
        __syncthreads();
    }

    // out[b][k] = p[k+1] - 1 for the K real columns
    for (int j = lane; j < K_; j += 64)
        out[b * K_ + j] = p_lds[j + 1] - 1;
}

// ------------------------------------------------------------------- launcher
extern "C" void kernel_launch(void* const* d_in, const int* in_sizes, int n_in,
                              void* d_out, int out_size, void* d_ws, size_t ws_size,
                              hipStream_t stream) {
    const float* mp = (const float*)d_in[0];   // meta_points
    const float* mv = (const float*)d_in[1];   // meta_visibles
    /* d_in[2] covisibles: unused by reference */
    const float* gt = (const float*)d_in[3];   // gtpoints
    const float* gv = (const float*)d_in[4];   // gtvisibles
    int* out = (int*)d_out;                    // int32 assignment indices
    float* cost = (float*)d_ws;                // 16*256*128 fp32 = 2 MB

    dim3 gridA(B_, M_);
    cost_kernel<<<gridA, K_, 0, stream>>>(mp, mv, gt, gv, cost);
    match_kernel<<<B_, 64, 0, stream>>>(cost, out);
}

// Round 12
// 1363.312 us; speedup vs baseline: 3.7555x; 1.5434x over previous
//
#include <hip/hip_runtime.h>
#include <math.h>

// Problem: MPMatcher  S=6, B=16, L=8, M=256, K=128
// Phase 1 (PASSING, DO NOT TOUCH): cost f32, ocml logf, *(1/6) reciprocal mean.
// Phase 2: reference's buggy greedy walk, f64-exact. R23 = exact revert to R15
// (best measured: match 1297us / total 1363us, absmax 0).
// Session conclusion (R12-R22 evidence): the kernel sits at an ALGORITHMIC
// SERIAL-LATENCY FLOOR, not a hardware roofline:
//   - 1882 serial iterations/block (measured via counter side-channels, R17:
//     1490 dummy-marches + 392 real-wins), 16 independent blocks -> only 16
//     of 256 CUs can be used; the walk is strictly sequential.
//   - per-iteration chain: 64-lane f64 argmin (6-stage DPP ladder, 3 inst/
//     stage via v_min_f64) -> readlane broadcast -> first-index extraction
//     (ballots) -> pointer-chase LDS row load (speculatively issued, shadow
//     work underneath).
//   - every structural alternative measured SLOWER: lookahead ladder (R13:
//     1418), depth-2 queue (R14: 1579), carried-(key,j) ladder (R22: 2104),
//     lazy row-min cache (R21: 2178), per-walk sort + static stop flags (R20:
//     3837), cached-argmin + fixup (R19: 5120). At 1 wave/CU, added
//     instructions cost more than the latency they hide.
// R15 content: R11 structure + fully-deferred dual updates (the 8 conditional
// per-iteration f64 dual updates removed; column chosen at running-sum U_j
// gets amt = usum_final - U_j at commit), software-pipelined speculative row
// load, value-DPP ladder + ballot extraction (R9), rows 1..128 pre-matched
// (R8), dummies never re-matched -> i0n = j1-128 statically.

#define S_ 6
#define B_ 16
#define L_ 8
#define M_ 256
#define K_ 128

// ---------------------------------------------------------------- cost kernel
__global__ void cost_kernel(const float* __restrict__ mp,   // (6,16,8,256,2)
                            const float* __restrict__ mv,   // (6,16,256,1)
                            const float* __restrict__ gt,   // (6,16,128,2)
                            const float* __restrict__ gv,   // (6,16,128,1)
                            float* __restrict__ cost)       // (16,256,128)
{
#pragma clang fp contract(off)
    const int b = blockIdx.x;
    const int m = blockIdx.y;
    const int k = threadIdx.x;

    float accS = 0.0f;
    for (int s = 0; s < S_; ++s) {
        const int sb = s * B_ + b;
        const float gx = gt[(sb * K_ + k) * 2 + 0];
        const float gy = gt[(sb * K_ + k) * 2 + 1];
        float accL = 0.0f;
#pragma unroll
        for (int l = 0; l < L_; ++l) {
            const int base = ((sb * L_ + l) * M_ + m) * 2;
            const float dx = fabsf(mp[base + 0] - gx);
            const float dy = fabsf(mp[base + 1] - gy);
            const float diff = dx + dy;
            const float dl = (float)(L_ - (l + 1)) * 0.05f;
            const float t = diff - dl;
            accL += fmaxf(t, 0.0f);
        }
        const float meanL = accL * 0.125f;
        const float mvv = mv[sb * M_ + m];
        const float gtv = gv[sb * K_ + k];
        const float lp = -logf(mvv);
        const float ln = -logf(1.0f - mvv);
        const float val = (gtv != 0.0f) ? (5.0f * meanL + lp) : ln;
        accS += val;
    }
    cost[(b * M_ + m) * K_ + k] = accS * (1.0f / 6.0f);
}

// --------------------------------------------------------------- bit helpers
__device__ __forceinline__ double bits2d(int lo, int hi) {
    const unsigned long long u =
        ((unsigned long long)(unsigned)hi << 32) | (unsigned)lo;
    return __longlong_as_double((long long)u);
}
__device__ __forceinline__ void d2bits(double d, int& lo, int& hi) {
    const unsigned long long u = (unsigned long long)__double_as_longlong(d);
    lo = (int)(u & 0xffffffffull);
    hi = (int)(u >> 32);
}

// ------------------------------------------------------------- matcher kernel
// One wave per batch. Lane owns real cols j=2*lane+1, 2*lane+2 (slots 0,1)
// and dummy cols j=2*lane+129, 2*lane+130 (slots 2,3).
__global__ __launch_bounds__(64, 1) void match_kernel(const float* __restrict__ cost,
                                                      int* __restrict__ out)
{
#pragma clang fp contract(off)
    const int b = blockIdx.x;
    const int lane = threadIdx.x;   // 0..63
    const float* C = cost + (size_t)b * M_ * K_;
    const double INF = __builtin_inf();
    const int BIG = 0x7fffffff;

    __shared__ float  C_lds[M_ * K_];   // 128 KB cost slab (row-major, = global)
    __shared__ double u_lds[257];       // u[0..256], 1-based rows
    __shared__ int    p_lds[257];       // p[j] = row matched to col j; 0 = free

    // stage the batch's cost slab into LDS (coalesced float4 copies)
    for (int t = lane; t < (M_ * K_) / 4; t += 64)
        ((float4*)C_lds)[t] = ((const float4*)C)[t];

    // rows 1..128 pre-matched to dummy cols 129..256 (exact, proven R8)
    for (int t = lane; t < 257; t += 64) {
        u_lds[t] = 0.0;
        p_lds[t] = (t >= 129) ? (t - 128) : 0;
    }
    __syncthreads();

    double v0 = 0.0, v1 = 0.0, v2 = 0.0, v3 = 0.0;  // column potentials

    for (int i = 129; i <= 256; ++i) {
        // ---- row start: snapshot caches. p static during walk; dummies never
        // re-matched (p[dummy j] = j-128 statically); u[p[j]] for free cols
        // never updated mid-walk -> snapshots valid for broadcasts.
        const int pj0 = p_lds[2 * lane + 1];
        const int pj1 = p_lds[2 * lane + 2];
        const double up0 = u_lds[pj0], up1 = u_lds[pj1];
        const double up2 = u_lds[2 * lane + 1];   // p[2*lane+129] = 2*lane+1
        const double up3 = u_lds[2 * lane + 2];   // p[2*lane+130] = 2*lane+2

        float2 cc = *(const float2*)(C_lds + (i - 1) * K_ + 2 * lane);
        double u_i0 = 0.0;
        int used = 0;
        int j1 = 0;
        double usum = 0.0;
        // usum snapshot at choice time for each owned slot (valid iff used bit)
        double Ua0 = 0.0, Ua1 = 0.0, Ua2 = 0.0, Ua3 = 0.0;

        for (;;) {
            // candidates: cur = (cost - u[i0]) - v   (exact ref op order, f64)
            double cd0 = ((double)cc.x - u_i0) - v0;
            double cd1 = ((double)cc.y - u_i0) - v1;
            double cd2 = (0.0 - u_i0) - v2;
            double cd3 = (0.0 - u_i0) - v3;
            if (used & 1) cd0 = INF;
            if (used & 2) cd1 = INF;
            if (used & 4) cd2 = INF;
            if (used & 8) cd3 = INF;

            // local value min (+-0 ambiguity harmless, proven R9/R10)
            const double m01 = fmin(cd0, cd1);
            const double m23 = fmin(cd2, cd3);
            double bv = fmin(m01, m23);

            // wave value-min via DPP ladder (VALU pipe), result in lane 63
            int lo, hi; d2bits(bv, lo, hi);
#define MIN_STAGE(CTRL, RM)                                                      \
            {                                                                    \
                const int nlo = __builtin_amdgcn_update_dpp(lo, lo, CTRL, RM, 0xf, false); \
                const int nhi = __builtin_amdgcn_update_dpp(hi, hi, CTRL, RM, 0xf, false); \
                const double mv2 = fmin(bits2d(lo, hi), bits2d(nlo, nhi));       \
                d2bits(mv2, lo, hi);                                             \
            }
            MIN_STAGE(0x111, 0xf)   // row_shr:1
            MIN_STAGE(0x112, 0xf)   // row_shr:2
            MIN_STAGE(0x114, 0xf)   // row_shr:4
            MIN_STAGE(0x118, 0xf)   // row_shr:8
            MIN_STAGE(0x142, 0xa)   // row_bcast:15 -> rows 1,3
            MIN_STAGE(0x143, 0xc)   // row_bcast:31 -> rows 2,3
#undef MIN_STAGE
            const int mlo = __builtin_amdgcn_readlane(lo, 63);
            const int mhi = __builtin_amdgcn_readlane(hi, 63);
            const double delta = bits2d(mlo, mhi);   // == min value (scalar)

            // first-index extraction: cd == delta marks min-achievers; lane
            // order == j order within each class; real js (<=128) < dummy js
            int jr = BIG;
            if (cd1 == delta) jr = 2 * lane + 2;
            if (cd0 == delta) jr = 2 * lane + 1;
            int jd = BIG;
            if (cd3 == delta) jd = 2 * lane + 130;
            if (cd2 == delta) jd = 2 * lane + 129;
            const unsigned long long br = __ballot(jr != BIG);
            const unsigned long long bd = __ballot(jd != BIG);
            const unsigned long long bb = br ? br : bd;
            const int cand = (br != 0ull) ? jr : jd;
            j1 = __builtin_amdgcn_readlane(cand, (int)__builtin_ctzll(bb));

            // next row: dummies are never re-matched -> p[j1] = j1-128 statically
            int ol, sl;
            if (j1 >= 129) { ol = (j1 - 129) >> 1; sl = 2 + ((j1 - 129) & 1); }
            else           { ol = (j1 - 1) >> 1;   sl = (j1 - 1) & 1; }
            const int psel = (sl == 0) ? pj0 : (sl == 1) ? pj1 : 0;
            const int i0n = (j1 >= 129) ? (j1 - 128)
                                        : __builtin_amdgcn_readlane(psel, ol);

            // speculative next-row load, issued ASAP (clamped; unused on break)
            const int rown = (i0n > 0 ? i0n : 1) - 1;
            const float2 ccn = *(const float2*)(C_lds + rown * K_ + 2 * lane);

            // ---- shadow work (under the load's latency) ----
            // duals are NOT updated per-iteration (deferred to commit); only
            // the running delta-sum advances (ref-equivalent: used cols are
            // INF-masked and free cols' duals never change mid-walk)
            usum += delta;

            // u[p[j1]] broadcast from owner's row-start snapshot
            const double usel = (sl == 0) ? up0 : (sl == 1) ? up1
                              : (sl == 2) ? up2 : up3;
            int ulo, uhi; d2bits(usel, ulo, uhi);
            const double u_n = bits2d(__builtin_amdgcn_readlane(ulo, ol),
                                      __builtin_amdgcn_readlane(uhi, ol));

            if (i0n == 0) break;    // free real column -> augment (way==0)

            // mark j1 used (it is j0 of the next iteration, ref marks at top)
            // and snapshot the running sum for the deferred update
            if (lane == ol) {
                used |= (1 << sl);
                if (sl == 0)      Ua0 = usum;
                else if (sl == 1) Ua1 = usum;
                else if (sl == 2) Ua2 = usum;
                else              Ua3 = usum;
            }
            u_i0 = u_n;
            cc = ccn;
        }

        // ---- commit: deferred dual updates. Column j chosen at snapshot U_j
        // accumulates amt = usum_final - U_j (== sum of all later deltas).
        // Distinct columns -> distinct rows -> no LDS write conflicts.
        __syncthreads();
        if (used & 1) { const double a = usum - Ua0; u_lds[pj0] = up0 + a; v0 -= a; }
        if (used & 2) { const double a = usum - Ua1; u_lds[pj1] = up1 + a; v1 -= a; }
        if (used & 4) { const double a = usum - Ua2; u_lds[2 * lane + 1] = up2 + a; v2 -= a; }
        if (used & 8) { const double a = usum - Ua3; u_lds[2 * lane + 2] = up3 + a; v3 -= a; }
        if (lane == 0) { p_lds[j1] = i; u_lds[i] = usum; }
        __syncthreads();
    }

    // out[b][k] = p[k+1] - 1 for the K real columns
    for (int j = lane; j < K_; j += 64)
        out[b * K_ + j] = p_lds[j + 1] - 1;
}

// ------------------------------------------------------------------- launcher
extern "C" void kernel_launch(void* const* d_in, const int* in_sizes, int n_in,
                              void* d_out, int out_size, void* d_ws, size_t ws_size,
                              hipStream_t stream) {
    const float* mp = (const float*)d_in[0];   // meta_points
    const float* mv = (const float*)d_in[1];   // meta_visibles
    /* d_in[2] covisibles: unused by reference */
    const float* gt = (const float*)d_in[3];   // gtpoints
    const float* gv = (const float*)d_in[4];   // gtvisibles
    int* out = (int*)d_out;                    // int32 assignment indices
    float* cost = (float*)d_ws;                // 16*256*128 fp32 = 2 MB

    dim3 gridA(B_, M_);
    cost_kernel<<<gridA, K_, 0, stream>>>(mp, mv, gt, gv, cost);
    match_kernel<<<B_, 64, 0, stream>>>(cost, out);
}